// Round 12
// baseline (437.694 us; speedup 1.0000x reference)
//
#include <hip/hip_runtime.h>

// ---------------------------------------------------------------------------
// res_rand_GAE round 12: barrier-free mgemm12 — GEMM1 (16x16x32, swapped)
// accumulators feed GEMM2 (16x16x16) DIRECTLY as B-fragments (layout match:
// node=l15, k=4lg+reg). No LDS, no barriers; weights stream global->reg.
// Outputs: x [N,128] ++ A [N,1] fp32 in d_out.
// ---------------------------------------------------------------------------

typedef unsigned short u16;
typedef short bf16x8 __attribute__((ext_vector_type(8)));
typedef short bf16x4 __attribute__((ext_vector_type(4)));
typedef unsigned short us8 __attribute__((ext_vector_type(8)));
typedef float f32x4 __attribute__((ext_vector_type(4)));

static inline int cdiv_ll(long long a, long long b) { return (int)((a + b - 1) / b); }

__device__ inline float bf2f(u16 u) {
    union { unsigned int i; float f; } v; v.i = ((unsigned int)u) << 16; return v.f;
}
__device__ inline u16 f2bf(float x) {   // round-to-nearest-even
    union { float f; unsigned int i; } v; v.f = x;
    unsigned int r = v.i + 0x7fffu + ((v.i >> 16) & 1u);
    return (u16)(r >> 16);
}

// ---- fused setup: cnt=0, Aout=bfc2, emb->bf16, W1^T, Wcat^T, Wfc1^T --------

__global__ __launch_bounds__(256) void setup_kernel(const float* __restrict__ emb,
                                                    const float* __restrict__ W1,
                                                    const float* __restrict__ W2,
                                                    const float* __restrict__ Wres,
                                                    const float* __restrict__ Wfc1,
                                                    const float* __restrict__ bfc2,
                                                    u16* __restrict__ embb,
                                                    u16* __restrict__ W1t,
                                                    u16* __restrict__ Wct,
                                                    u16* __restrict__ Wfc1t,
                                                    int* __restrict__ cnt,
                                                    float* __restrict__ Aout,
                                                    int N) {
    long long r = (long long)blockIdx.x * 256 + threadIdx.x;
    const long long nf2b = (long long)N * 32;          // float4s of emb
    if (r < nf2b) {
        float4 v = ((const float4*)emb)[r];
        uint2 o;
        o.x = (unsigned)f2bf(v.x) | ((unsigned)f2bf(v.y) << 16);
        o.y = (unsigned)f2bf(v.z) | ((unsigned)f2bf(v.w) << 16);
        ((uint2*)embb)[r] = o;
        return;
    }
    r -= nf2b;
    if (r < 512 * 128) {                               // W1t[n*128+k] = W1[k*512+n]
        int n = (int)(r / 128), k = (int)(r % 128);
        W1t[r] = f2bf(W1[(size_t)k * 512 + n]);
        return;
    }
    r -= 512 * 128;
    if (r < 256 * 512) {                               // Wct[n*512+k]
        int n = (int)(r / 512), k = (int)(r % 512);
        float v = (n < 128) ? W2[(size_t)k * 128 + n] : Wres[(size_t)k * 128 + (n - 128)];
        Wct[r] = f2bf(v);
        return;
    }
    r -= 256 * 512;
    if (r < 256 * 128) {                               // Wfc1t[n*128+k]
        int n = (int)(r / 128), k = (int)(r % 128);
        Wfc1t[r] = f2bf(Wfc1[(size_t)k * 256 + n]);
        return;
    }
    r -= 256 * 128;
    if (r < N) { cnt[(int)r] = 0; return; }
    r -= N;
    if (r < N) Aout[(int)r] = bfc2[0];
}

// ---- CSR build -------------------------------------------------------------

__global__ __launch_bounds__(256) void hist_kernel(const int* __restrict__ dst,
                                                   int* __restrict__ cnt, int E) {
    int e = blockIdx.x * 256 + threadIdx.x;
    if (e < E) atomicAdd(&cnt[dst[e]], 1);
}

__global__ __launch_bounds__(256) void scanA_kernel(const int* __restrict__ cnt,
                                                    int* __restrict__ excl,
                                                    int* __restrict__ bsum, int N) {
    __shared__ int tmp[256];
    int i = blockIdx.x * 256 + threadIdx.x;
    int v = (i < N) ? cnt[i] : 0;
    tmp[threadIdx.x] = v;
    __syncthreads();
    for (int o = 1; o < 256; o <<= 1) {
        int t = (threadIdx.x >= (unsigned)o) ? tmp[threadIdx.x - o] : 0;
        __syncthreads();
        tmp[threadIdx.x] += t;
        __syncthreads();
    }
    if (i < N) excl[i] = tmp[threadIdx.x] - v;
    if (threadIdx.x == 255) bsum[blockIdx.x] = tmp[255];
}

// scanC2: block j reduces bsum[0..j-1] itself (no scanB launch)
__global__ __launch_bounds__(256) void scanC2_kernel(const int* __restrict__ excl,
                                                     const int* __restrict__ bsum,
                                                     const int* __restrict__ cnt,
                                                     int* __restrict__ rowptr,
                                                     int* __restrict__ cursor,
                                                     float* __restrict__ dinv,
                                                     int N, int E) {
    __shared__ int tmp[256];
    int t = threadIdx.x;
    tmp[t] = (t < (int)blockIdx.x) ? bsum[t] : 0;
    __syncthreads();
    for (int o = 128; o; o >>= 1) {
        if (t < o) tmp[t] += tmp[t + o];
        __syncthreads();
    }
    int pre = tmp[0];
    int i = blockIdx.x * 256 + t;
    if (i < N) {
        int r = excl[i] + pre;
        rowptr[i] = r;
        cursor[i] = r;
        dinv[i] = rsqrtf((float)cnt[i] + 2.0f);
    }
    if (i == 0) rowptr[N] = E;
}

__global__ __launch_bounds__(256) void fill_kernel(const int* __restrict__ src,
                                                   const int* __restrict__ dst,
                                                   const float* __restrict__ dinv,
                                                   int* __restrict__ cursor,
                                                   int* __restrict__ csr_src,
                                                   float* __restrict__ csr_w, int E) {
    int e = blockIdx.x * 256 + threadIdx.x;
    if (e >= E) return;
    int s = src[e], d = dst[e];
    int idx = atomicAdd(&cursor[d], 1);
    csr_src[idx] = s;
    csr_w[idx] = dinv[s] * dinv[d];
}

// ---- wave-per-node CSR aggregation over flat bf16 table [N][128] -----------

#define AGG_EDGE(SR, WR)                                                       \
    {                                                                          \
        unsigned int vv = hp[(size_t)(SR) * 64 + lane];                        \
        ax = fmaf(bf2f((u16)vv), (WR), ax);                                    \
        ay = fmaf(bf2f((u16)(vv >> 16)), (WR), ay);                            \
    }

__device__ inline void agg_row(const unsigned int* __restrict__ hp,
                               const int* __restrict__ rowptr,
                               const int* __restrict__ csr_src,
                               const float* __restrict__ csr_w,
                               const float* __restrict__ dinv,
                               int wid, int lane, float& ax, float& ay) {
    float dv = dinv[wid];
    unsigned int hv = hp[(size_t)wid * 64 + lane];
    float c0 = 2.0f * dv * dv;
    ax = bf2f((u16)hv) * c0;
    ay = bf2f((u16)(hv >> 16)) * c0;
    int e = rowptr[wid], e1 = rowptr[wid + 1];
    for (; e + 7 < e1; e += 8) {
        int s0 = csr_src[e + 0], s1 = csr_src[e + 1], s2 = csr_src[e + 2], s3 = csr_src[e + 3];
        int s4 = csr_src[e + 4], s5 = csr_src[e + 5], s6 = csr_src[e + 6], s7 = csr_src[e + 7];
        float w0 = csr_w[e + 0], w1 = csr_w[e + 1], w2 = csr_w[e + 2], w3 = csr_w[e + 3];
        float w4 = csr_w[e + 4], w5 = csr_w[e + 5], w6 = csr_w[e + 6], w7 = csr_w[e + 7];
        AGG_EDGE(s0, w0); AGG_EDGE(s1, w1); AGG_EDGE(s2, w2); AGG_EDGE(s3, w3);
        AGG_EDGE(s4, w4); AGG_EDGE(s5, w5); AGG_EDGE(s6, w6); AGG_EDGE(s7, w7);
    }
    if (e + 3 < e1) {
        int s0 = csr_src[e + 0], s1 = csr_src[e + 1], s2 = csr_src[e + 2], s3 = csr_src[e + 3];
        float w0 = csr_w[e + 0], w1 = csr_w[e + 1], w2 = csr_w[e + 2], w3 = csr_w[e + 3];
        AGG_EDGE(s0, w0); AGG_EDGE(s1, w1); AGG_EDGE(s2, w2); AGG_EDGE(s3, w3);
        e += 4;
    }
    for (; e < e1; ++e) {
        int s0 = csr_src[e]; float w0 = csr_w[e];
        AGG_EDGE(s0, w0);
    }
}

__global__ __launch_bounds__(256) void aggb_kernel(const u16* __restrict__ hb,
                                                   const int* __restrict__ rowptr,
                                                   const int* __restrict__ csr_src,
                                                   const float* __restrict__ csr_w,
                                                   const float* __restrict__ dinv,
                                                   u16* __restrict__ out, int N) {
    int wid  = (blockIdx.x * blockDim.x + threadIdx.x) >> 6;
    int lane = threadIdx.x & 63;
    if (wid >= N) return;
    float ax, ay;
    agg_row((const unsigned int*)hb, rowptr, csr_src, csr_w, dinv, wid, lane, ax, ay);
    ((unsigned int*)out)[(size_t)wid * 64 + lane] =
        (unsigned)f2bf(ax) | ((unsigned)f2bf(ay) << 16);
}

// fused: x = relu(agg(h2) + b2) + hres + bres -> xout fp32 (in-place)
__global__ __launch_bounds__(256) void aggfin_kernel(const u16* __restrict__ hb,
                                                     const int* __restrict__ rowptr,
                                                     const int* __restrict__ csr_src,
                                                     const float* __restrict__ csr_w,
                                                     const float* __restrict__ dinv,
                                                     const float* __restrict__ b2,
                                                     const float* __restrict__ bres,
                                                     float* __restrict__ xout, int N) {
    int wid  = (blockIdx.x * blockDim.x + threadIdx.x) >> 6;
    int lane = threadIdx.x & 63;
    if (wid >= N) return;
    float ax, ay;
    agg_row((const unsigned int*)hb, rowptr, csr_src, csr_w, dinv, wid, lane, ax, ay);
    float2 bb = ((const float2*)b2)[lane];
    float2 rr = ((const float2*)bres)[lane];
    float2 hres = ((float2*)xout)[(size_t)wid * 64 + lane];
    float ox = fmaxf(ax + bb.x, 0.f) + hres.x + rr.x;
    float oy = fmaxf(ay + bb.y, 0.f) + hres.y + rr.y;
    ((float2*)xout)[(size_t)wid * 64 + lane] = make_float2(ox, oy);
}

// ---- fused GEMM1+GEMM2, barrier-free, register-only -------------------------
// 64 nodes/block, 4 waves x 16 nodes (node = base + l15). Per pass p (128
// x1-cols): GEMM1 = 32x mfma_16x16x32 (swapped: W1t as A, agg as B) ->
// acc1[q] holds x1[node=l15][128p+16q+4lg+reg]. That IS the B-fragment of
// mfma_16x16x16 (n=l15, k=4lg+j): bias+relu+cvt then GEMM2 = 128x
// mfma_16x16x16 into acc2[fn2] (col2 = 16fn2+4lg+reg, node = l15).
// No LDS, no __syncthreads -> compiler pipelines the weight streams freely.

__global__ __launch_bounds__(256) void mgemm12(const u16* __restrict__ aggE,
                                               const u16* __restrict__ W1t,
                                               const u16* __restrict__ Wct,
                                               const float* __restrict__ b1,
                                               int M,
                                               u16* __restrict__ h2b,
                                               float* __restrict__ xout) {
    const int t = threadIdx.x;
    const int wv = t >> 6;
    const int lane = t & 63;
    const int l15 = lane & 15, lg = lane >> 4;
    const int node = blockIdx.x * 64 + wv * 16 + l15;

    // agg fragments: agg[node][32ks+8lg..+7], constant across passes
    bf16x8 afr[4];
#pragma unroll
    for (int ks = 0; ks < 4; ++ks) {
        bf16x8 v = (bf16x8)(short)0;
        if (node < M)
            v = *(const bf16x8*)(aggE + (size_t)node * 128 + 32 * ks + 8 * lg);
        afr[ks] = v;
    }

    f32x4 acc2[16];
#pragma unroll
    for (int i = 0; i < 16; ++i) acc2[i] = (f32x4)(0.0f);

    for (int p = 0; p < 4; ++p) {
        // GEMM1: acc1[q] = x1[node][128p+16q+4lg+reg] (pre-bias)
        f32x4 acc1[8];
#pragma unroll
        for (int i = 0; i < 8; ++i) acc1[i] = (f32x4)(0.0f);
#pragma unroll
        for (int ks = 0; ks < 4; ++ks) {
#pragma unroll
            for (int q = 0; q < 8; ++q) {
                bf16x8 w1f = *(const bf16x8*)(W1t +
                    (size_t)(128 * p + 16 * q + l15) * 128 + 32 * ks + 8 * lg);
                acc1[q] = __builtin_amdgcn_mfma_f32_16x16x32_bf16(
                    w1f, afr[ks], acc1[q], 0, 0, 0);
            }
        }

        // GEMM2: consume acc1[q] directly as 16x16x16 B-fragments
#pragma unroll
        for (int q = 0; q < 8; ++q) {
            const int c1 = 128 * p + 16 * q + 4 * lg;
            float4 b4 = *(const float4*)&b1[c1];
            bf16x4 xf;
            xf[0] = (short)f2bf(fmaxf(acc1[q][0] + b4.x, 0.f));
            xf[1] = (short)f2bf(fmaxf(acc1[q][1] + b4.y, 0.f));
            xf[2] = (short)f2bf(fmaxf(acc1[q][2] + b4.z, 0.f));
            xf[3] = (short)f2bf(fmaxf(acc1[q][3] + b4.w, 0.f));
#pragma unroll
            for (int fn2 = 0; fn2 < 16; ++fn2) {
                bf16x4 w2f = *(const bf16x4*)(Wct +
                    (size_t)(16 * fn2 + l15) * 512 + c1);
                acc2[fn2] = __builtin_amdgcn_mfma_f32_16x16x16bf16_1k(
                    w2f, xf, acc2[fn2], 0, 0, 0);
            }
        }
    }

    // epilogue: node = l15-lane's node; col2 = 16fn2 + 4lg + reg
    if (node < M) {
#pragma unroll
        for (int fn2 = 0; fn2 < 16; ++fn2) {
            const int col = 16 * fn2 + 4 * lg;
            f32x4 v = acc2[fn2];
            if (col < 128) {                      // h2 -> bf16
                uint2 o;
                o.x = (unsigned)f2bf(v[0]) | ((unsigned)f2bf(v[1]) << 16);
                o.y = (unsigned)f2bf(v[2]) | ((unsigned)f2bf(v[3]) << 16);
                *(uint2*)(h2b + (size_t)node * 128 + col) = o;
            } else {                              // hres -> fp32
                *(float4*)(xout + (size_t)node * 128 + (col - 128)) =
                    make_float4(v[0], v[1], v[2], v[3]);
            }
        }
    }
}

// ---- head GEMM: A[row] += sum_col relu((x@Wfc1t)[row][col]+bfc1)*Wfc2 ------
// A operand read as fp32 from xout, converted to bf16 during LDS staging.

__global__ __launch_bounds__(512) void head_gemm(const float* __restrict__ X,
                                                 const u16* __restrict__ Bt,
                                                 int M,
                                                 const float* __restrict__ bias,
                                                 const float* __restrict__ w2,
                                                 float* __restrict__ Cf) {
    __shared__ u16 As[128][72];
    __shared__ u16 Bs[256][72];
    const int t = threadIdx.x;
    const int bm = blockIdx.x * 128;
    const int w = t >> 6, lane = t & 63;
    const int wm = w >> 2, wn = w & 3;
    const int l15 = lane & 15, lg = lane >> 4;
    const int srow = t >> 3, scol = (t & 7) * 8;
    const int K = 128;

    f32x4 acc[4][4];
#pragma unroll
    for (int i = 0; i < 4; ++i)
#pragma unroll
        for (int j = 0; j < 4; ++j) acc[i][j] = (f32x4)(0.0f);

    for (int kk = 0; kk < K; kk += 64) {
#pragma unroll
        for (int i = 0; i < 2; ++i) {
            int row = srow + 64 * i;
            uint4 o = make_uint4(0u, 0u, 0u, 0u);
            if (bm + row < M) {
                const float* src = X + (size_t)(bm + row) * K + kk + scol;
                float4 a = *(const float4*)src;
                float4 b = *(const float4*)(src + 4);
                o.x = (unsigned)f2bf(a.x) | ((unsigned)f2bf(a.y) << 16);
                o.y = (unsigned)f2bf(a.z) | ((unsigned)f2bf(a.w) << 16);
                o.z = (unsigned)f2bf(b.x) | ((unsigned)f2bf(b.y) << 16);
                o.w = (unsigned)f2bf(b.z) | ((unsigned)f2bf(b.w) << 16);
            }
            *(uint4*)&As[row][scol] = o;
        }
#pragma unroll
        for (int i = 0; i < 4; ++i) {
            int row = srow + 64 * i;
            *(us8*)&Bs[row][scol] =
                *(const us8*)(Bt + (size_t)row * K + kk + scol);
        }
        __syncthreads();
#pragma unroll
        for (int ks = 0; ks < 2; ++ks) {
            const int ko = 32 * ks + lg * 8;
            bf16x8 bfr[4], afr[4];
#pragma unroll
            for (int fn = 0; fn < 4; ++fn)
                bfr[fn] = *(const bf16x8*)&Bs[64 * wn + 16 * fn + l15][ko];
#pragma unroll
            for (int fm = 0; fm < 4; ++fm)
                afr[fm] = *(const bf16x8*)&As[64 * wm + 16 * fm + l15][ko];
#pragma unroll
            for (int fm = 0; fm < 4; ++fm)
#pragma unroll
                for (int fn = 0; fn < 4; ++fn)
                    acc[fm][fn] = __builtin_amdgcn_mfma_f32_16x16x32_bf16(
                        bfr[fn], afr[fm], acc[fm][fn], 0, 0, 0);
        }
        __syncthreads();
    }

    float4 bl4[4], wl4[4];
#pragma unroll
    for (int fn = 0; fn < 4; ++fn) {
        int c = 64 * wn + 16 * fn + 4 * lg;
        bl4[fn] = *(const float4*)&bias[c];
        wl4[fn] = *(const float4*)&w2[c];
    }
#pragma unroll
    for (int fm = 0; fm < 4; ++fm) {
        float p = 0.f;
#pragma unroll
        for (int fn = 0; fn < 4; ++fn) {
            p += fmaxf(acc[fm][fn][0] + bl4[fn].x, 0.f) * wl4[fn].x;
            p += fmaxf(acc[fm][fn][1] + bl4[fn].y, 0.f) * wl4[fn].y;
            p += fmaxf(acc[fm][fn][2] + bl4[fn].z, 0.f) * wl4[fn].z;
            p += fmaxf(acc[fm][fn][3] + bl4[fn].w, 0.f) * wl4[fn].w;
        }
        p += __shfl_xor(p, 16);
        p += __shfl_xor(p, 32);
        int row = bm + 64 * wm + 16 * fm + l15;
        if (lane < 16 && row < M) atomicAdd(&Cf[row], p);
    }
}

// ---------------------------------------------------------------------------

extern "C" void kernel_launch(void* const* d_in, const int* in_sizes, int n_in,
                              void* d_out, int out_size, void* d_ws, size_t ws_size,
                              hipStream_t stream) {
    const float* emb  = (const float*)d_in[0];
    const int*   eidx = (const int*)d_in[1];
    const float* W1   = (const float*)d_in[2];
    const float* b1   = (const float*)d_in[3];
    const float* W2   = (const float*)d_in[4];
    const float* b2   = (const float*)d_in[5];
    const float* Wres = (const float*)d_in[6];
    const float* bres = (const float*)d_in[7];
    const float* Wfc1 = (const float*)d_in[8];
    const float* bfc1 = (const float*)d_in[9];
    const float* Wfc2 = (const float*)d_in[10];
    const float* bfc2 = (const float*)d_in[11];

    const int N = in_sizes[0] / 128;
    const int E = in_sizes[1] / 2;
    const int* srcv = eidx;
    const int* dstv = eidx + E;

    float* out  = (float*)d_out;
    float* xout = out;                       // [N,128]
    float* Aout = out + (size_t)N * 128;     // [N]

    // ---- workspace layout ----
    char* p = (char*)d_ws;
    float* dinv  = (float*)p;            p += (size_t)N * 4;
    float* csr_w = (float*)p;            p += (size_t)E * 4;
    u16*  embb   = (u16*)p;              p += (size_t)N * 128 * 2;   // flat [N][128]
    u16*  aggEb  = (u16*)p;              p += (size_t)N * 128 * 2;   // flat [N][128]
    u16*  h2b    = (u16*)p;              p += (size_t)N * 128 * 2;   // flat [N][128]
    u16*  W1t    = (u16*)p;              p += (size_t)512 * 128 * 2;
    u16*  Wct    = (u16*)p;              p += (size_t)256 * 512 * 2;
    u16*  Wfc1t  = (u16*)p;              p += (size_t)256 * 128 * 2;
    int*  cnt     = (int*)p;             p += (size_t)N * 4;
    int*  excl    = (int*)p;             p += (size_t)N * 4;
    int*  rowptr  = (int*)p;             p += (size_t)(N + 1) * 4;
    int*  cursor  = (int*)p;             p += (size_t)N * 4;
    int*  bsum    = (int*)p;             p += 256 * 4;
    int*  csr_src = (int*)p;             p += (size_t)E * 4;

    const int T  = 256;
    const int nb = cdiv_ll(N, 256);      // <= 256 required by scanC2

    // 1) fused setup (also zeroes cnt, inits Aout=bfc2)
    const long long setup_work = (long long)N * 32 + 512 * 128 + 256 * 512
                               + 256 * 128 + (long long)N + (long long)N;
    setup_kernel<<<cdiv_ll(setup_work, T), T, 0, stream>>>(
        emb, W1, W2, Wres, Wfc1, bfc2, embb, W1t, Wct, Wfc1t, cnt, Aout, N);

    // 2) CSR build + dinv
    hist_kernel<<<cdiv_ll(E, T), T, 0, stream>>>(dstv, cnt, E);
    scanA_kernel<<<nb, T, 0, stream>>>(cnt, excl, bsum, N);
    scanC2_kernel<<<nb, T, 0, stream>>>(excl, bsum, cnt, rowptr, cursor, dinv, N, E);
    fill_kernel<<<cdiv_ll(E, T), T, 0, stream>>>(srcv, dstv, dinv, cursor, csr_src, csr_w, E);

    // 3) aggE = S @ emb  (flat bf16)
    aggb_kernel<<<cdiv_ll((long long)N * 64, T), T, 0, stream>>>(
        embb, rowptr, csr_src, csr_w, dinv, aggEb, N);

    // 4) fused GEMM1+GEMM2 (barrier-free): h2 = relu(aggE@W1+b1)@W2 (bf16),
    //    hres = relu(aggE@W1+b1)@Wres (fp32 -> xout)
    mgemm12<<<cdiv_ll(N, 64), 256, 0, stream>>>(
        aggEb, W1t, Wct, b1, N, h2b, xout);

    // 5) fused: x = relu(S@h2 + b2) + hres + bres -> xout (fp32, in-place)
    aggfin_kernel<<<cdiv_ll((long long)N * 64, T), T, 0, stream>>>(
        h2b, rowptr, csr_src, csr_w, dinv, b2, bres, xout, N);

    // 6) head: A += sum relu(x@Wfc1t + bfc1) * Wfc2  (A pre-init to bfc2)
    head_gemm<<<cdiv_ll(N, 128), 512, 0, stream>>>(
        xout, Wfc1t, N, bfc1, Wfc2, Aout);
}

// Round 13
// 262.727 us; speedup vs baseline: 1.6660x; 1.6660x over previous
//
#include <hip/hip_runtime.h>

// ---------------------------------------------------------------------------
// res_rand_GAE round 13: mgemm12 = LDS-staged weights (coalesced, 71.7 KB ->
// 2 blocks/CU) + register x1 handoff (GEMM1 acc feeds GEMM2 x16-MFMA B-frag
// directly; no X1s LDS). BM=64, 4 waves m-split. A-fragments in registers.
// Outputs: x [N,128] ++ A [N,1] fp32 in d_out.
// ---------------------------------------------------------------------------

typedef unsigned short u16;
typedef short bf16x8 __attribute__((ext_vector_type(8)));
typedef short bf16x4 __attribute__((ext_vector_type(4)));
typedef unsigned short us8 __attribute__((ext_vector_type(8)));
typedef float f32x4 __attribute__((ext_vector_type(4)));

static inline int cdiv_ll(long long a, long long b) { return (int)((a + b - 1) / b); }

__device__ inline float bf2f(u16 u) {
    union { unsigned int i; float f; } v; v.i = ((unsigned int)u) << 16; return v.f;
}
__device__ inline u16 f2bf(float x) {   // round-to-nearest-even
    union { float f; unsigned int i; } v; v.f = x;
    unsigned int r = v.i + 0x7fffu + ((v.i >> 16) & 1u);
    return (u16)(r >> 16);
}

// ---- fused setup: cnt=0, Aout=bfc2, emb->bf16, W1^T, Wcat^T, Wfc1^T --------

__global__ __launch_bounds__(256) void setup_kernel(const float* __restrict__ emb,
                                                    const float* __restrict__ W1,
                                                    const float* __restrict__ W2,
                                                    const float* __restrict__ Wres,
                                                    const float* __restrict__ Wfc1,
                                                    const float* __restrict__ bfc2,
                                                    u16* __restrict__ embb,
                                                    u16* __restrict__ W1t,
                                                    u16* __restrict__ Wct,
                                                    u16* __restrict__ Wfc1t,
                                                    int* __restrict__ cnt,
                                                    float* __restrict__ Aout,
                                                    int N) {
    long long r = (long long)blockIdx.x * 256 + threadIdx.x;
    const long long nf2b = (long long)N * 32;          // float4s of emb
    if (r < nf2b) {
        float4 v = ((const float4*)emb)[r];
        uint2 o;
        o.x = (unsigned)f2bf(v.x) | ((unsigned)f2bf(v.y) << 16);
        o.y = (unsigned)f2bf(v.z) | ((unsigned)f2bf(v.w) << 16);
        ((uint2*)embb)[r] = o;
        return;
    }
    r -= nf2b;
    if (r < 512 * 128) {                               // W1t[n*128+k] = W1[k*512+n]
        int n = (int)(r / 128), k = (int)(r % 128);
        W1t[r] = f2bf(W1[(size_t)k * 512 + n]);
        return;
    }
    r -= 512 * 128;
    if (r < 256 * 512) {                               // Wct[n*512+k]
        int n = (int)(r / 512), k = (int)(r % 512);
        float v = (n < 128) ? W2[(size_t)k * 128 + n] : Wres[(size_t)k * 128 + (n - 128)];
        Wct[r] = f2bf(v);
        return;
    }
    r -= 256 * 512;
    if (r < 256 * 128) {                               // Wfc1t[n*128+k]
        int n = (int)(r / 128), k = (int)(r % 128);
        Wfc1t[r] = f2bf(Wfc1[(size_t)k * 256 + n]);
        return;
    }
    r -= 256 * 128;
    if (r < N) { cnt[(int)r] = 0; return; }
    r -= N;
    if (r < N) Aout[(int)r] = bfc2[0];
}

// ---- CSR build -------------------------------------------------------------

__global__ __launch_bounds__(256) void hist_kernel(const int* __restrict__ dst,
                                                   int* __restrict__ cnt, int E) {
    int e = blockIdx.x * 256 + threadIdx.x;
    if (e < E) atomicAdd(&cnt[dst[e]], 1);
}

__global__ __launch_bounds__(256) void scanA_kernel(const int* __restrict__ cnt,
                                                    int* __restrict__ excl,
                                                    int* __restrict__ bsum, int N) {
    __shared__ int tmp[256];
    int i = blockIdx.x * 256 + threadIdx.x;
    int v = (i < N) ? cnt[i] : 0;
    tmp[threadIdx.x] = v;
    __syncthreads();
    for (int o = 1; o < 256; o <<= 1) {
        int t = (threadIdx.x >= (unsigned)o) ? tmp[threadIdx.x - o] : 0;
        __syncthreads();
        tmp[threadIdx.x] += t;
        __syncthreads();
    }
    if (i < N) excl[i] = tmp[threadIdx.x] - v;
    if (threadIdx.x == 255) bsum[blockIdx.x] = tmp[255];
}

// scanC2: block j reduces bsum[0..j-1] itself (no scanB launch)
__global__ __launch_bounds__(256) void scanC2_kernel(const int* __restrict__ excl,
                                                     const int* __restrict__ bsum,
                                                     const int* __restrict__ cnt,
                                                     int* __restrict__ rowptr,
                                                     int* __restrict__ cursor,
                                                     float* __restrict__ dinv,
                                                     int N, int E) {
    __shared__ int tmp[256];
    int t = threadIdx.x;
    tmp[t] = (t < (int)blockIdx.x) ? bsum[t] : 0;
    __syncthreads();
    for (int o = 128; o; o >>= 1) {
        if (t < o) tmp[t] += tmp[t + o];
        __syncthreads();
    }
    int pre = tmp[0];
    int i = blockIdx.x * 256 + t;
    if (i < N) {
        int r = excl[i] + pre;
        rowptr[i] = r;
        cursor[i] = r;
        dinv[i] = rsqrtf((float)cnt[i] + 2.0f);
    }
    if (i == 0) rowptr[N] = E;
}

__global__ __launch_bounds__(256) void fill_kernel(const int* __restrict__ src,
                                                   const int* __restrict__ dst,
                                                   const float* __restrict__ dinv,
                                                   int* __restrict__ cursor,
                                                   int* __restrict__ csr_src,
                                                   float* __restrict__ csr_w, int E) {
    int e = blockIdx.x * 256 + threadIdx.x;
    if (e >= E) return;
    int s = src[e], d = dst[e];
    int idx = atomicAdd(&cursor[d], 1);
    csr_src[idx] = s;
    csr_w[idx] = dinv[s] * dinv[d];
}

// ---- wave-per-node CSR aggregation over flat bf16 table [N][128] -----------

#define AGG_EDGE(SR, WR)                                                       \
    {                                                                          \
        unsigned int vv = hp[(size_t)(SR) * 64 + lane];                        \
        ax = fmaf(bf2f((u16)vv), (WR), ax);                                    \
        ay = fmaf(bf2f((u16)(vv >> 16)), (WR), ay);                            \
    }

__device__ inline void agg_row(const unsigned int* __restrict__ hp,
                               const int* __restrict__ rowptr,
                               const int* __restrict__ csr_src,
                               const float* __restrict__ csr_w,
                               const float* __restrict__ dinv,
                               int wid, int lane, float& ax, float& ay) {
    float dv = dinv[wid];
    unsigned int hv = hp[(size_t)wid * 64 + lane];
    float c0 = 2.0f * dv * dv;
    ax = bf2f((u16)hv) * c0;
    ay = bf2f((u16)(hv >> 16)) * c0;
    int e = rowptr[wid], e1 = rowptr[wid + 1];
    for (; e + 7 < e1; e += 8) {
        int s0 = csr_src[e + 0], s1 = csr_src[e + 1], s2 = csr_src[e + 2], s3 = csr_src[e + 3];
        int s4 = csr_src[e + 4], s5 = csr_src[e + 5], s6 = csr_src[e + 6], s7 = csr_src[e + 7];
        float w0 = csr_w[e + 0], w1 = csr_w[e + 1], w2 = csr_w[e + 2], w3 = csr_w[e + 3];
        float w4 = csr_w[e + 4], w5 = csr_w[e + 5], w6 = csr_w[e + 6], w7 = csr_w[e + 7];
        AGG_EDGE(s0, w0); AGG_EDGE(s1, w1); AGG_EDGE(s2, w2); AGG_EDGE(s3, w3);
        AGG_EDGE(s4, w4); AGG_EDGE(s5, w5); AGG_EDGE(s6, w6); AGG_EDGE(s7, w7);
    }
    if (e + 3 < e1) {
        int s0 = csr_src[e + 0], s1 = csr_src[e + 1], s2 = csr_src[e + 2], s3 = csr_src[e + 3];
        float w0 = csr_w[e + 0], w1 = csr_w[e + 1], w2 = csr_w[e + 2], w3 = csr_w[e + 3];
        AGG_EDGE(s0, w0); AGG_EDGE(s1, w1); AGG_EDGE(s2, w2); AGG_EDGE(s3, w3);
        e += 4;
    }
    for (; e < e1; ++e) {
        int s0 = csr_src[e]; float w0 = csr_w[e];
        AGG_EDGE(s0, w0);
    }
}

__global__ __launch_bounds__(256) void aggb_kernel(const u16* __restrict__ hb,
                                                   const int* __restrict__ rowptr,
                                                   const int* __restrict__ csr_src,
                                                   const float* __restrict__ csr_w,
                                                   const float* __restrict__ dinv,
                                                   u16* __restrict__ out, int N) {
    int wid  = (blockIdx.x * blockDim.x + threadIdx.x) >> 6;
    int lane = threadIdx.x & 63;
    if (wid >= N) return;
    float ax, ay;
    agg_row((const unsigned int*)hb, rowptr, csr_src, csr_w, dinv, wid, lane, ax, ay);
    ((unsigned int*)out)[(size_t)wid * 64 + lane] =
        (unsigned)f2bf(ax) | ((unsigned)f2bf(ay) << 16);
}

// fused: x = relu(agg(h2) + b2) + hres + bres -> xout fp32 (in-place)
__global__ __launch_bounds__(256) void aggfin_kernel(const u16* __restrict__ hb,
                                                     const int* __restrict__ rowptr,
                                                     const int* __restrict__ csr_src,
                                                     const float* __restrict__ csr_w,
                                                     const float* __restrict__ dinv,
                                                     const float* __restrict__ b2,
                                                     const float* __restrict__ bres,
                                                     float* __restrict__ xout, int N) {
    int wid  = (blockIdx.x * blockDim.x + threadIdx.x) >> 6;
    int lane = threadIdx.x & 63;
    if (wid >= N) return;
    float ax, ay;
    agg_row((const unsigned int*)hb, rowptr, csr_src, csr_w, dinv, wid, lane, ax, ay);
    float2 bb = ((const float2*)b2)[lane];
    float2 rr = ((const float2*)bres)[lane];
    float2 hres = ((float2*)xout)[(size_t)wid * 64 + lane];
    float ox = fmaxf(ax + bb.x, 0.f) + hres.x + rr.x;
    float oy = fmaxf(ay + bb.y, 0.f) + hres.y + rr.y;
    ((float2*)xout)[(size_t)wid * 64 + lane] = make_float2(ox, oy);
}

// ---- fused GEMM1+GEMM2: LDS weights + register x1 handoff -------------------
// BM=64 nodes/block, 4 waves m-split (wave wv owns nodes 16wv..16wv+15,
// node = base + 16wv + l15). Per pass p (128 x1-cols):
//   stage Ws <- W1t[128p..][128]      (coalesced, 32 KB)
//   GEMM1: acc1[q] = x1[node][128p+16q+4lg+reg], 32x mfma_16x16x32 (swapped)
//   stage Ws <- Wct[0:256][128p..]    (coalesced, 64 KB)
//   GEMM2: xf = relu(acc1[q]+b1) cvt bf16x4 — EXACTLY the 16x16x16 B-frag
//          (n=l15, k=4lg+reg); acc2[fn2] += mfma16(Ws-frag, xf): 128x/pass
// LDS = 256*140*2 = 71.7 KB -> 2 blocks/CU for cross-block barrier overlap.

__global__ __launch_bounds__(256) void mgemm12(const u16* __restrict__ aggE,
                                               const u16* __restrict__ W1t,
                                               const u16* __restrict__ Wct,
                                               const float* __restrict__ b1,
                                               int M,
                                               u16* __restrict__ h2b,
                                               float* __restrict__ xout) {
    extern __shared__ u16 Ws[];        // [256][140]
    const int LD = 140;
    const int t = threadIdx.x;
    const int wv = t >> 6;             // 0..3
    const int lane = t & 63;
    const int l15 = lane & 15, lg = lane >> 4;
    const int node = blockIdx.x * 64 + wv * 16 + l15;

    // A fragments: agg[node][32ks+8lg..+7], constant across passes
    bf16x8 afr[4];
#pragma unroll
    for (int ks = 0; ks < 4; ++ks) {
        bf16x8 v = (bf16x8)(short)0;
        if (node < M)
            v = *(const bf16x8*)(aggE + (size_t)node * 128 + 32 * ks + 8 * lg);
        afr[ks] = v;
    }

    f32x4 acc2[16];
#pragma unroll
    for (int i = 0; i < 16; ++i) acc2[i] = (f32x4)(0.0f);

    for (int p = 0; p < 4; ++p) {
        __syncthreads();               // prior GEMM2 done reading Ws
        // stage Ws[0:128] <- W1t rows [128p .. 128p+128), 128 u16 each
#pragma unroll
        for (int i = 0; i < 8; ++i) {
            int c = t + 256 * i;       // 0..2047
            int row = c >> 4, ch = (c & 15) * 8;
            *(us8*)&Ws[row * LD + ch] =
                *(const us8*)(W1t + (size_t)(128 * p + row) * 128 + ch);
        }
        __syncthreads();

        // GEMM1: acc1[q] = x1[node][128p+16q+4lg+reg] (pre-bias)
        f32x4 acc1[8];
#pragma unroll
        for (int i = 0; i < 8; ++i) acc1[i] = (f32x4)(0.0f);
#pragma unroll
        for (int ks = 0; ks < 4; ++ks) {
#pragma unroll
            for (int q = 0; q < 8; ++q) {
                bf16x8 w1f = *(const bf16x8*)&Ws[(16 * q + l15) * LD + 32 * ks + 8 * lg];
                acc1[q] = __builtin_amdgcn_mfma_f32_16x16x32_bf16(
                    w1f, afr[ks], acc1[q], 0, 0, 0);
            }
        }
        __syncthreads();               // GEMM1 done reading Ws

        // stage Ws[0:256] <- Wct k-slice [0:256][128p .. 128p+128)
#pragma unroll
        for (int i = 0; i < 16; ++i) {
            int c = t + 256 * i;       // 0..4095
            int row = c >> 4, ch = (c & 15) * 8;
            *(us8*)&Ws[row * LD + ch] =
                *(const us8*)(Wct + (size_t)row * 512 + 128 * p + ch);
        }
        __syncthreads();

        // GEMM2: consume acc1[q] directly as 16x16x16 B-fragments
#pragma unroll
        for (int q = 0; q < 8; ++q) {
            const int c1 = 128 * p + 16 * q + 4 * lg;
            float4 b4 = *(const float4*)&b1[c1];
            bf16x4 xf;
            xf[0] = (short)f2bf(fmaxf(acc1[q][0] + b4.x, 0.f));
            xf[1] = (short)f2bf(fmaxf(acc1[q][1] + b4.y, 0.f));
            xf[2] = (short)f2bf(fmaxf(acc1[q][2] + b4.z, 0.f));
            xf[3] = (short)f2bf(fmaxf(acc1[q][3] + b4.w, 0.f));
#pragma unroll
            for (int fn2 = 0; fn2 < 16; ++fn2) {
                bf16x4 w2f = *(const bf16x4*)&Ws[(16 * fn2 + l15) * LD + 16 * q + 4 * lg];
                acc2[fn2] = __builtin_amdgcn_mfma_f32_16x16x16bf16_1k(
                    w2f, xf, acc2[fn2], 0, 0, 0);
            }
        }
    }

    // epilogue: node-row = l15; col = 16fn2 + 4lg + reg
    if (node < M) {
#pragma unroll
        for (int fn2 = 0; fn2 < 16; ++fn2) {
            const int col = 16 * fn2 + 4 * lg;
            f32x4 v = acc2[fn2];
            if (col < 128) {                      // h2 -> bf16
                uint2 o;
                o.x = (unsigned)f2bf(v[0]) | ((unsigned)f2bf(v[1]) << 16);
                o.y = (unsigned)f2bf(v[2]) | ((unsigned)f2bf(v[3]) << 16);
                *(uint2*)(h2b + (size_t)node * 128 + col) = o;
            } else {                              // hres -> fp32
                *(float4*)(xout + (size_t)node * 128 + (col - 128)) =
                    make_float4(v[0], v[1], v[2], v[3]);
            }
        }
    }
}

// ---- head GEMM: A[row] += sum_col relu((x@Wfc1t)[row][col]+bfc1)*Wfc2 ------
// A operand read as fp32 from xout, converted to bf16 during LDS staging.

__global__ __launch_bounds__(512) void head_gemm(const float* __restrict__ X,
                                                 const u16* __restrict__ Bt,
                                                 int M,
                                                 const float* __restrict__ bias,
                                                 const float* __restrict__ w2,
                                                 float* __restrict__ Cf) {
    __shared__ u16 As[128][72];
    __shared__ u16 Bs[256][72];
    const int t = threadIdx.x;
    const int bm = blockIdx.x * 128;
    const int w = t >> 6, lane = t & 63;
    const int wm = w >> 2, wn = w & 3;
    const int l15 = lane & 15, lg = lane >> 4;
    const int srow = t >> 3, scol = (t & 7) * 8;
    const int K = 128;

    f32x4 acc[4][4];
#pragma unroll
    for (int i = 0; i < 4; ++i)
#pragma unroll
        for (int j = 0; j < 4; ++j) acc[i][j] = (f32x4)(0.0f);

    for (int kk = 0; kk < K; kk += 64) {
#pragma unroll
        for (int i = 0; i < 2; ++i) {
            int row = srow + 64 * i;
            uint4 o = make_uint4(0u, 0u, 0u, 0u);
            if (bm + row < M) {
                const float* src = X + (size_t)(bm + row) * K + kk + scol;
                float4 a = *(const float4*)src;
                float4 b = *(const float4*)(src + 4);
                o.x = (unsigned)f2bf(a.x) | ((unsigned)f2bf(a.y) << 16);
                o.y = (unsigned)f2bf(a.z) | ((unsigned)f2bf(a.w) << 16);
                o.z = (unsigned)f2bf(b.x) | ((unsigned)f2bf(b.y) << 16);
                o.w = (unsigned)f2bf(b.z) | ((unsigned)f2bf(b.w) << 16);
            }
            *(uint4*)&As[row][scol] = o;
        }
#pragma unroll
        for (int i = 0; i < 4; ++i) {
            int row = srow + 64 * i;
            *(us8*)&Bs[row][scol] =
                *(const us8*)(Bt + (size_t)row * K + kk + scol);
        }
        __syncthreads();
#pragma unroll
        for (int ks = 0; ks < 2; ++ks) {
            const int ko = 32 * ks + lg * 8;
            bf16x8 bfr[4], afr[4];
#pragma unroll
            for (int fn = 0; fn < 4; ++fn)
                bfr[fn] = *(const bf16x8*)&Bs[64 * wn + 16 * fn + l15][ko];
#pragma unroll
            for (int fm = 0; fm < 4; ++fm)
                afr[fm] = *(const bf16x8*)&As[64 * wm + 16 * fm + l15][ko];
#pragma unroll
            for (int fm = 0; fm < 4; ++fm)
#pragma unroll
                for (int fn = 0; fn < 4; ++fn)
                    acc[fm][fn] = __builtin_amdgcn_mfma_f32_16x16x32_bf16(
                        bfr[fn], afr[fm], acc[fm][fn], 0, 0, 0);
        }
        __syncthreads();
    }

    float4 bl4[4], wl4[4];
#pragma unroll
    for (int fn = 0; fn < 4; ++fn) {
        int c = 64 * wn + 16 * fn + 4 * lg;
        bl4[fn] = *(const float4*)&bias[c];
        wl4[fn] = *(const float4*)&w2[c];
    }
#pragma unroll
    for (int fm = 0; fm < 4; ++fm) {
        float p = 0.f;
#pragma unroll
        for (int fn = 0; fn < 4; ++fn) {
            p += fmaxf(acc[fm][fn][0] + bl4[fn].x, 0.f) * wl4[fn].x;
            p += fmaxf(acc[fm][fn][1] + bl4[fn].y, 0.f) * wl4[fn].y;
            p += fmaxf(acc[fm][fn][2] + bl4[fn].z, 0.f) * wl4[fn].z;
            p += fmaxf(acc[fm][fn][3] + bl4[fn].w, 0.f) * wl4[fn].w;
        }
        p += __shfl_xor(p, 16);
        p += __shfl_xor(p, 32);
        int row = bm + 64 * wm + 16 * fm + l15;
        if (lane < 16 && row < M) atomicAdd(&Cf[row], p);
    }
}

// ---------------------------------------------------------------------------

extern "C" void kernel_launch(void* const* d_in, const int* in_sizes, int n_in,
                              void* d_out, int out_size, void* d_ws, size_t ws_size,
                              hipStream_t stream) {
    const float* emb  = (const float*)d_in[0];
    const int*   eidx = (const int*)d_in[1];
    const float* W1   = (const float*)d_in[2];
    const float* b1   = (const float*)d_in[3];
    const float* W2   = (const float*)d_in[4];
    const float* b2   = (const float*)d_in[5];
    const float* Wres = (const float*)d_in[6];
    const float* bres = (const float*)d_in[7];
    const float* Wfc1 = (const float*)d_in[8];
    const float* bfc1 = (const float*)d_in[9];
    const float* Wfc2 = (const float*)d_in[10];
    const float* bfc2 = (const float*)d_in[11];

    const int N = in_sizes[0] / 128;
    const int E = in_sizes[1] / 2;
    const int* srcv = eidx;
    const int* dstv = eidx + E;

    float* out  = (float*)d_out;
    float* xout = out;                       // [N,128]
    float* Aout = out + (size_t)N * 128;     // [N]

    // ---- workspace layout ----
    char* p = (char*)d_ws;
    float* dinv  = (float*)p;            p += (size_t)N * 4;
    float* csr_w = (float*)p;            p += (size_t)E * 4;
    u16*  embb   = (u16*)p;              p += (size_t)N * 128 * 2;   // flat [N][128]
    u16*  aggEb  = (u16*)p;              p += (size_t)N * 128 * 2;   // flat [N][128]
    u16*  h2b    = (u16*)p;              p += (size_t)N * 128 * 2;   // flat [N][128]
    u16*  W1t    = (u16*)p;              p += (size_t)512 * 128 * 2;
    u16*  Wct    = (u16*)p;              p += (size_t)256 * 512 * 2;
    u16*  Wfc1t  = (u16*)p;              p += (size_t)256 * 128 * 2;
    int*  cnt     = (int*)p;             p += (size_t)N * 4;
    int*  excl    = (int*)p;             p += (size_t)N * 4;
    int*  rowptr  = (int*)p;             p += (size_t)(N + 1) * 4;
    int*  cursor  = (int*)p;             p += (size_t)N * 4;
    int*  bsum    = (int*)p;             p += 256 * 4;
    int*  csr_src = (int*)p;             p += (size_t)E * 4;

    const int T  = 256;
    const int nb = cdiv_ll(N, 256);      // <= 256 required by scanC2

    // 1) fused setup (also zeroes cnt, inits Aout=bfc2)
    const long long setup_work = (long long)N * 32 + 512 * 128 + 256 * 512
                               + 256 * 128 + (long long)N + (long long)N;
    setup_kernel<<<cdiv_ll(setup_work, T), T, 0, stream>>>(
        emb, W1, W2, Wres, Wfc1, bfc2, embb, W1t, Wct, Wfc1t, cnt, Aout, N);

    // 2) CSR build + dinv
    hist_kernel<<<cdiv_ll(E, T), T, 0, stream>>>(dstv, cnt, E);
    scanA_kernel<<<nb, T, 0, stream>>>(cnt, excl, bsum, N);
    scanC2_kernel<<<nb, T, 0, stream>>>(excl, bsum, cnt, rowptr, cursor, dinv, N, E);
    fill_kernel<<<cdiv_ll(E, T), T, 0, stream>>>(srcv, dstv, dinv, cursor, csr_src, csr_w, E);

    // 3) aggE = S @ emb  (flat bf16)
    aggb_kernel<<<cdiv_ll((long long)N * 64, T), T, 0, stream>>>(
        embb, rowptr, csr_src, csr_w, dinv, aggEb, N);

    // 4) fused GEMM1+GEMM2: h2 = relu(aggE@W1+b1)@W2 (bf16), hres -> xout fp32
    const size_t lds12 = (size_t)256 * 140 * sizeof(u16);   // 71,680 B
    mgemm12<<<cdiv_ll(N, 64), 256, lds12, stream>>>(
        aggEb, W1t, Wct, b1, N, h2b, xout);

    // 5) fused: x = relu(S@h2 + b2) + hres + bres -> xout (fp32, in-place)
    aggfin_kernel<<<cdiv_ll((long long)N * 64, T), T, 0, stream>>>(
        h2b, rowptr, csr_src, csr_w, dinv, b2, bres, xout, N);

    // 6) head: A += sum relu(x@Wfc1t + bfc1) * Wfc2  (A pre-init to bfc2)
    head_gemm<<<cdiv_ll(N, 128), 512, 0, stream>>>(
        xout, Wfc1t, N, bfc1, Wfc2, Aout);
}

// Round 15
// 174.929 us; speedup vs baseline: 2.5021x; 1.5019x over previous
//
#include <hip/hip_runtime.h>

// ---------------------------------------------------------------------------
// res_rand_GAE round 15: consolidation of best validated pieces.
// = r10 structure (setup, CSR+scanC2, flat aggb, prefetched mgemm12)
// + r11's aggfin (no xb side-write) + r11's head_gemm (fp32 x read, cvt in
// staging). Outputs: x [N,128] ++ A [N,1] fp32 in d_out.
// ---------------------------------------------------------------------------

typedef unsigned short u16;
typedef short bf16x8 __attribute__((ext_vector_type(8)));
typedef unsigned short us8 __attribute__((ext_vector_type(8)));
typedef float f32x4 __attribute__((ext_vector_type(4)));

static inline int cdiv_ll(long long a, long long b) { return (int)((a + b - 1) / b); }

__device__ inline float bf2f(u16 u) {
    union { unsigned int i; float f; } v; v.i = ((unsigned int)u) << 16; return v.f;
}
__device__ inline u16 f2bf(float x) {   // round-to-nearest-even
    union { float f; unsigned int i; } v; v.f = x;
    unsigned int r = v.i + 0x7fffu + ((v.i >> 16) & 1u);
    return (u16)(r >> 16);
}

// ---- fused setup: cnt=0, Aout=bfc2, emb->bf16, W1^T, Wcat^T, Wfc1^T --------

__global__ __launch_bounds__(256) void setup_kernel(const float* __restrict__ emb,
                                                    const float* __restrict__ W1,
                                                    const float* __restrict__ W2,
                                                    const float* __restrict__ Wres,
                                                    const float* __restrict__ Wfc1,
                                                    const float* __restrict__ bfc2,
                                                    u16* __restrict__ embb,
                                                    u16* __restrict__ W1t,
                                                    u16* __restrict__ Wct,
                                                    u16* __restrict__ Wfc1t,
                                                    int* __restrict__ cnt,
                                                    float* __restrict__ Aout,
                                                    int N) {
    long long r = (long long)blockIdx.x * 256 + threadIdx.x;
    const long long nf2b = (long long)N * 32;          // float4s of emb
    if (r < nf2b) {
        float4 v = ((const float4*)emb)[r];
        uint2 o;
        o.x = (unsigned)f2bf(v.x) | ((unsigned)f2bf(v.y) << 16);
        o.y = (unsigned)f2bf(v.z) | ((unsigned)f2bf(v.w) << 16);
        ((uint2*)embb)[r] = o;
        return;
    }
    r -= nf2b;
    if (r < 512 * 128) {                               // W1t[n*128+k] = W1[k*512+n]
        int n = (int)(r / 128), k = (int)(r % 128);
        W1t[r] = f2bf(W1[(size_t)k * 512 + n]);
        return;
    }
    r -= 512 * 128;
    if (r < 256 * 512) {                               // Wct[n*512+k]
        int n = (int)(r / 512), k = (int)(r % 512);
        float v = (n < 128) ? W2[(size_t)k * 128 + n] : Wres[(size_t)k * 128 + (n - 128)];
        Wct[r] = f2bf(v);
        return;
    }
    r -= 256 * 512;
    if (r < 256 * 128) {                               // Wfc1t[n*128+k]
        int n = (int)(r / 128), k = (int)(r % 128);
        Wfc1t[r] = f2bf(Wfc1[(size_t)k * 256 + n]);
        return;
    }
    r -= 256 * 128;
    if (r < N) { cnt[(int)r] = 0; return; }
    r -= N;
    if (r < N) Aout[(int)r] = bfc2[0];
}

// ---- CSR build -------------------------------------------------------------

__global__ __launch_bounds__(256) void hist_kernel(const int* __restrict__ dst,
                                                   int* __restrict__ cnt, int E) {
    int e = blockIdx.x * 256 + threadIdx.x;
    if (e < E) atomicAdd(&cnt[dst[e]], 1);
}

__global__ __launch_bounds__(256) void scanA_kernel(const int* __restrict__ cnt,
                                                    int* __restrict__ excl,
                                                    int* __restrict__ bsum, int N) {
    __shared__ int tmp[256];
    int i = blockIdx.x * 256 + threadIdx.x;
    int v = (i < N) ? cnt[i] : 0;
    tmp[threadIdx.x] = v;
    __syncthreads();
    for (int o = 1; o < 256; o <<= 1) {
        int t = (threadIdx.x >= (unsigned)o) ? tmp[threadIdx.x - o] : 0;
        __syncthreads();
        tmp[threadIdx.x] += t;
        __syncthreads();
    }
    if (i < N) excl[i] = tmp[threadIdx.x] - v;
    if (threadIdx.x == 255) bsum[blockIdx.x] = tmp[255];
}

// scanC2: block j reduces bsum[0..j-1] itself (no scanB launch)
__global__ __launch_bounds__(256) void scanC2_kernel(const int* __restrict__ excl,
                                                     const int* __restrict__ bsum,
                                                     const int* __restrict__ cnt,
                                                     int* __restrict__ rowptr,
                                                     int* __restrict__ cursor,
                                                     float* __restrict__ dinv,
                                                     int N, int E) {
    __shared__ int tmp[256];
    int t = threadIdx.x;
    tmp[t] = (t < (int)blockIdx.x) ? bsum[t] : 0;
    __syncthreads();
    for (int o = 128; o; o >>= 1) {
        if (t < o) tmp[t] += tmp[t + o];
        __syncthreads();
    }
    int pre = tmp[0];
    int i = blockIdx.x * 256 + t;
    if (i < N) {
        int r = excl[i] + pre;
        rowptr[i] = r;
        cursor[i] = r;
        dinv[i] = rsqrtf((float)cnt[i] + 2.0f);
    }
    if (i == 0) rowptr[N] = E;
}

__global__ __launch_bounds__(256) void fill_kernel(const int* __restrict__ src,
                                                   const int* __restrict__ dst,
                                                   const float* __restrict__ dinv,
                                                   int* __restrict__ cursor,
                                                   int* __restrict__ csr_src,
                                                   float* __restrict__ csr_w, int E) {
    int e = blockIdx.x * 256 + threadIdx.x;
    if (e >= E) return;
    int s = src[e], d = dst[e];
    int idx = atomicAdd(&cursor[d], 1);
    csr_src[idx] = s;
    csr_w[idx] = dinv[s] * dinv[d];
}

// ---- wave-per-node CSR aggregation over flat bf16 table [N][128] -----------

#define AGG_EDGE(SR, WR)                                                       \
    {                                                                          \
        unsigned int vv = hp[(size_t)(SR) * 64 + lane];                        \
        ax = fmaf(bf2f((u16)vv), (WR), ax);                                    \
        ay = fmaf(bf2f((u16)(vv >> 16)), (WR), ay);                            \
    }

__device__ inline void agg_row(const unsigned int* __restrict__ hp,
                               const int* __restrict__ rowptr,
                               const int* __restrict__ csr_src,
                               const float* __restrict__ csr_w,
                               const float* __restrict__ dinv,
                               int wid, int lane, float& ax, float& ay) {
    float dv = dinv[wid];
    unsigned int hv = hp[(size_t)wid * 64 + lane];
    float c0 = 2.0f * dv * dv;
    ax = bf2f((u16)hv) * c0;
    ay = bf2f((u16)(hv >> 16)) * c0;
    int e = rowptr[wid], e1 = rowptr[wid + 1];
    for (; e + 7 < e1; e += 8) {
        int s0 = csr_src[e + 0], s1 = csr_src[e + 1], s2 = csr_src[e + 2], s3 = csr_src[e + 3];
        int s4 = csr_src[e + 4], s5 = csr_src[e + 5], s6 = csr_src[e + 6], s7 = csr_src[e + 7];
        float w0 = csr_w[e + 0], w1 = csr_w[e + 1], w2 = csr_w[e + 2], w3 = csr_w[e + 3];
        float w4 = csr_w[e + 4], w5 = csr_w[e + 5], w6 = csr_w[e + 6], w7 = csr_w[e + 7];
        AGG_EDGE(s0, w0); AGG_EDGE(s1, w1); AGG_EDGE(s2, w2); AGG_EDGE(s3, w3);
        AGG_EDGE(s4, w4); AGG_EDGE(s5, w5); AGG_EDGE(s6, w6); AGG_EDGE(s7, w7);
    }
    if (e + 3 < e1) {
        int s0 = csr_src[e + 0], s1 = csr_src[e + 1], s2 = csr_src[e + 2], s3 = csr_src[e + 3];
        float w0 = csr_w[e + 0], w1 = csr_w[e + 1], w2 = csr_w[e + 2], w3 = csr_w[e + 3];
        AGG_EDGE(s0, w0); AGG_EDGE(s1, w1); AGG_EDGE(s2, w2); AGG_EDGE(s3, w3);
        e += 4;
    }
    for (; e < e1; ++e) {
        int s0 = csr_src[e]; float w0 = csr_w[e];
        AGG_EDGE(s0, w0);
    }
}

__global__ __launch_bounds__(256) void aggb_kernel(const u16* __restrict__ hb,
                                                   const int* __restrict__ rowptr,
                                                   const int* __restrict__ csr_src,
                                                   const float* __restrict__ csr_w,
                                                   const float* __restrict__ dinv,
                                                   u16* __restrict__ out, int N) {
    int wid  = (blockIdx.x * blockDim.x + threadIdx.x) >> 6;
    int lane = threadIdx.x & 63;
    if (wid >= N) return;
    float ax, ay;
    agg_row((const unsigned int*)hb, rowptr, csr_src, csr_w, dinv, wid, lane, ax, ay);
    ((unsigned int*)out)[(size_t)wid * 64 + lane] =
        (unsigned)f2bf(ax) | ((unsigned)f2bf(ay) << 16);
}

// fused: x = relu(agg(h2) + b2) + hres + bres -> xout fp32 (in-place)
__global__ __launch_bounds__(256) void aggfin_kernel(const u16* __restrict__ hb,
                                                     const int* __restrict__ rowptr,
                                                     const int* __restrict__ csr_src,
                                                     const float* __restrict__ csr_w,
                                                     const float* __restrict__ dinv,
                                                     const float* __restrict__ b2,
                                                     const float* __restrict__ bres,
                                                     float* __restrict__ xout, int N) {
    int wid  = (blockIdx.x * blockDim.x + threadIdx.x) >> 6;
    int lane = threadIdx.x & 63;
    if (wid >= N) return;
    float ax, ay;
    agg_row((const unsigned int*)hb, rowptr, csr_src, csr_w, dinv, wid, lane, ax, ay);
    float2 bb = ((const float2*)b2)[lane];
    float2 rr = ((const float2*)bres)[lane];
    float2 hres = ((float2*)xout)[(size_t)wid * 64 + lane];
    float ox = fmaxf(ax + bb.x, 0.f) + hres.x + rr.x;
    float oy = fmaxf(ay + bb.y, 0.f) + hres.y + rr.y;
    ((float2*)xout)[(size_t)wid * 64 + lane] = make_float2(ox, oy);
}

// ---- fused GEMM1+GEMM2 with register-prefetched weight staging (r10) --------
// Per 128-row block: x1 = relu(aggE@W1 + b1) in 4 passes of 128 cols; each
// pass's slice -> LDS -> GEMM2 k-accumulate (h2 = x1@W2 bf16; hres = x1@Wres
// fp32). Wct slice loads issue before GEMM1's MFMAs; next W1t slice loads
// issue before GEMM2's MFMAs -> global latency hidden under compute.
// 512 threads = 8 waves (2x4). Swapped-operand MFMA.
// Dynamic LDS: Ag[128][136] | Ws[256][136] | X1s[128][136]  (139,264 B)

__global__ __launch_bounds__(512) void mgemm12(const u16* __restrict__ aggE,
                                               const u16* __restrict__ W1t,
                                               const u16* __restrict__ Wct,
                                               const float* __restrict__ b1,
                                               int M,
                                               u16* __restrict__ h2b,
                                               float* __restrict__ xout) {
    extern __shared__ u16 smem[];
    u16* Ag  = smem;                    // [128][136]
    u16* Ws  = Ag + 128 * 136;          // [256][136]
    u16* X1s = Ws + 256 * 136;          // [128][136]
    const int LD = 136;

    const int t = threadIdx.x;
    const int bm = blockIdx.x * 128;
    const int w = t >> 6, lane = t & 63;
    const int wm = w >> 2, wn = w & 3;        // 2 x 4 wave grid
    const int l15 = lane & 15, lg = lane >> 4;
    const int srow = t >> 4, scol = (t & 15) * 8;   // staging coords (row 0..31 +32*i)

    // stage aggE tile [128][128] (zero-pad rows >= M)
#pragma unroll
    for (int i = 0; i < 4; ++i) {
        int row = srow + 32 * i;
        us8 v = (us8)(u16)0;
        if (bm + row < M) v = *(const us8*)(aggE + (size_t)(bm + row) * 128 + scol);
        *(us8*)&Ag[row * LD + scol] = v;
    }

    f32x4 acc2[4][4];
#pragma unroll
    for (int i = 0; i < 4; ++i)
#pragma unroll
        for (int j = 0; j < 4; ++j) acc2[i][j] = (f32x4)(0.0f);

    us8 rw1[4], rwc[8];
    // prologue: preload pass-0 W1t slice into registers
#pragma unroll
    for (int i = 0; i < 4; ++i)
        rw1[i] = *(const us8*)(W1t + (size_t)(srow + 32 * i) * 128 + scol);

    for (int p = 0; p < 4; ++p) {
        __syncthreads();   // Ws free (prior GEMM2 done); Ag stores visible (p=0)
        // Ws <- rw1 (W1t slice, 128 rows)
#pragma unroll
        for (int i = 0; i < 4; ++i)
            *(us8*)&Ws[(srow + 32 * i) * LD + scol] = rw1[i];
        __syncthreads();

        // issue this pass's Wct slice loads (land during GEMM1)
#pragma unroll
        for (int i = 0; i < 8; ++i)
            rwc[i] = *(const us8*)(Wct + (size_t)(srow + 32 * i) * 512 + 128 * p + scol);

        // GEMM1: x1 slice [128 rows][128 cols], K = 128
        f32x4 acc1[4][2];
#pragma unroll
        for (int i = 0; i < 4; ++i)
#pragma unroll
            for (int j = 0; j < 2; ++j) acc1[i][j] = (f32x4)(0.0f);
#pragma unroll
        for (int ks = 0; ks < 4; ++ks) {
            const int ko = 32 * ks + lg * 8;
            bf16x8 wfr[2], afr[4];
#pragma unroll
            for (int fn = 0; fn < 2; ++fn)
                wfr[fn] = *(const bf16x8*)&Ws[(32 * wn + 16 * fn + l15) * LD + ko];
#pragma unroll
            for (int fm = 0; fm < 4; ++fm)
                afr[fm] = *(const bf16x8*)&Ag[(64 * wm + 16 * fm + l15) * LD + ko];
#pragma unroll
            for (int fm = 0; fm < 4; ++fm)
#pragma unroll
                for (int fn = 0; fn < 2; ++fn)
                    acc1[fm][fn] = __builtin_amdgcn_mfma_f32_16x16x32_bf16(
                        wfr[fn], afr[fm], acc1[fm][fn], 0, 0, 0);
        }
        __syncthreads();   // Ws reads done

        // write x1 slice (bias+relu, bf16) to X1s
#pragma unroll
        for (int fm = 0; fm < 4; ++fm) {
#pragma unroll
            for (int fn = 0; fn < 2; ++fn) {
                int col1 = 32 * wn + 16 * fn + 4 * lg;         // 0..124
                float4 b4 = *(const float4*)&b1[128 * p + col1];
                f32x4 v = acc1[fm][fn];
                float v0 = fmaxf(v[0] + b4.x, 0.f), v1 = fmaxf(v[1] + b4.y, 0.f);
                float v2 = fmaxf(v[2] + b4.z, 0.f), v3 = fmaxf(v[3] + b4.w, 0.f);
                uint2 o;
                o.x = (unsigned)f2bf(v0) | ((unsigned)f2bf(v1) << 16);
                o.y = (unsigned)f2bf(v2) | ((unsigned)f2bf(v3) << 16);
                *(uint2*)&X1s[(64 * wm + 16 * fm + l15) * LD + col1] = o;
            }
        }
        // Ws <- rwc (Wct slice, 256 rows)
#pragma unroll
        for (int i = 0; i < 8; ++i)
            *(us8*)&Ws[(srow + 32 * i) * LD + scol] = rwc[i];
        // issue next pass's W1t slice loads (land during GEMM2)
        if (p < 3) {
#pragma unroll
            for (int i = 0; i < 4; ++i)
                rw1[i] = *(const us8*)(W1t + (size_t)(128 * (p + 1) + srow + 32 * i) * 128 + scol);
        }
        __syncthreads();

        // GEMM2 accumulate: acc2 += Wct-slice x x1-slice (k = 128)
#pragma unroll
        for (int ks = 0; ks < 4; ++ks) {
            const int ko = 32 * ks + lg * 8;
            bf16x8 wfr[4], xfr[4];
#pragma unroll
            for (int fn = 0; fn < 4; ++fn)
                wfr[fn] = *(const bf16x8*)&Ws[(64 * wn + 16 * fn + l15) * LD + ko];
#pragma unroll
            for (int fm = 0; fm < 4; ++fm)
                xfr[fm] = *(const bf16x8*)&X1s[(64 * wm + 16 * fm + l15) * LD + ko];
#pragma unroll
            for (int fm = 0; fm < 4; ++fm)
#pragma unroll
                for (int fn = 0; fn < 4; ++fn)
                    acc2[fm][fn] = __builtin_amdgcn_mfma_f32_16x16x32_bf16(
                        wfr[fn], xfr[fm], acc2[fm][fn], 0, 0, 0);
        }
    }

    // epilogue: row = bm+64wm+16fm+l15; col = 64wn+16fn+4lg
#pragma unroll
    for (int fm = 0; fm < 4; ++fm) {
        const int row = bm + 64 * wm + 16 * fm + l15;
        if (row >= M) continue;
#pragma unroll
        for (int fn = 0; fn < 4; ++fn) {
            const int col = 64 * wn + 16 * fn + 4 * lg;
            f32x4 v = acc2[fm][fn];
            if (col < 128) {                      // h2 -> bf16
                uint2 o;
                o.x = (unsigned)f2bf(v[0]) | ((unsigned)f2bf(v[1]) << 16);
                o.y = (unsigned)f2bf(v[2]) | ((unsigned)f2bf(v[3]) << 16);
                *(uint2*)(h2b + (size_t)row * 128 + col) = o;
            } else {                              // hres -> fp32
                *(float4*)(xout + (size_t)row * 128 + (col - 128)) =
                    make_float4(v[0], v[1], v[2], v[3]);
            }
        }
    }
}

// ---- head GEMM: A[row] += sum_col relu((x@Wfc1t)[row][col]+bfc1)*Wfc2 ------
// A operand read as fp32 from xout, converted to bf16 during LDS staging.

__global__ __launch_bounds__(512) void head_gemm(const float* __restrict__ X,
                                                 const u16* __restrict__ Bt,
                                                 int M,
                                                 const float* __restrict__ bias,
                                                 const float* __restrict__ w2,
                                                 float* __restrict__ Cf) {
    __shared__ u16 As[128][72];
    __shared__ u16 Bs[256][72];
    const int t = threadIdx.x;
    const int bm = blockIdx.x * 128;
    const int w = t >> 6, lane = t & 63;
    const int wm = w >> 2, wn = w & 3;
    const int l15 = lane & 15, lg = lane >> 4;
    const int srow = t >> 3, scol = (t & 7) * 8;
    const int K = 128;

    f32x4 acc[4][4];
#pragma unroll
    for (int i = 0; i < 4; ++i)
#pragma unroll
        for (int j = 0; j < 4; ++j) acc[i][j] = (f32x4)(0.0f);

    for (int kk = 0; kk < K; kk += 64) {
#pragma unroll
        for (int i = 0; i < 2; ++i) {
            int row = srow + 64 * i;
            uint4 o = make_uint4(0u, 0u, 0u, 0u);
            if (bm + row < M) {
                const float* src = X + (size_t)(bm + row) * K + kk + scol;
                float4 a = *(const float4*)src;
                float4 b = *(const float4*)(src + 4);
                o.x = (unsigned)f2bf(a.x) | ((unsigned)f2bf(a.y) << 16);
                o.y = (unsigned)f2bf(a.z) | ((unsigned)f2bf(a.w) << 16);
                o.z = (unsigned)f2bf(b.x) | ((unsigned)f2bf(b.y) << 16);
                o.w = (unsigned)f2bf(b.z) | ((unsigned)f2bf(b.w) << 16);
            }
            *(uint4*)&As[row][scol] = o;
        }
#pragma unroll
        for (int i = 0; i < 4; ++i) {
            int row = srow + 64 * i;
            *(us8*)&Bs[row][scol] =
                *(const us8*)(Bt + (size_t)row * K + kk + scol);
        }
        __syncthreads();
#pragma unroll
        for (int ks = 0; ks < 2; ++ks) {
            const int ko = 32 * ks + lg * 8;
            bf16x8 bfr[4], afr[4];
#pragma unroll
            for (int fn = 0; fn < 4; ++fn)
                bfr[fn] = *(const bf16x8*)&Bs[64 * wn + 16 * fn + l15][ko];
#pragma unroll
            for (int fm = 0; fm < 4; ++fm)
                afr[fm] = *(const bf16x8*)&As[64 * wm + 16 * fm + l15][ko];
#pragma unroll
            for (int fm = 0; fm < 4; ++fm)
#pragma unroll
                for (int fn = 0; fn < 4; ++fn)
                    acc[fm][fn] = __builtin_amdgcn_mfma_f32_16x16x32_bf16(
                        bfr[fn], afr[fm], acc[fm][fn], 0, 0, 0);
        }
        __syncthreads();
    }

    float4 bl4[4], wl4[4];
#pragma unroll
    for (int fn = 0; fn < 4; ++fn) {
        int c = 64 * wn + 16 * fn + 4 * lg;
        bl4[fn] = *(const float4*)&bias[c];
        wl4[fn] = *(const float4*)&w2[c];
    }
#pragma unroll
    for (int fm = 0; fm < 4; ++fm) {
        float p = 0.f;
#pragma unroll
        for (int fn = 0; fn < 4; ++fn) {
            p += fmaxf(acc[fm][fn][0] + bl4[fn].x, 0.f) * wl4[fn].x;
            p += fmaxf(acc[fm][fn][1] + bl4[fn].y, 0.f) * wl4[fn].y;
            p += fmaxf(acc[fm][fn][2] + bl4[fn].z, 0.f) * wl4[fn].z;
            p += fmaxf(acc[fm][fn][3] + bl4[fn].w, 0.f) * wl4[fn].w;
        }
        p += __shfl_xor(p, 16);
        p += __shfl_xor(p, 32);
        int row = bm + 64 * wm + 16 * fm + l15;
        if (lane < 16 && row < M) atomicAdd(&Cf[row], p);
    }
}

// ---------------------------------------------------------------------------

extern "C" void kernel_launch(void* const* d_in, const int* in_sizes, int n_in,
                              void* d_out, int out_size, void* d_ws, size_t ws_size,
                              hipStream_t stream) {
    const float* emb  = (const float*)d_in[0];
    const int*   eidx = (const int*)d_in[1];
    const float* W1   = (const float*)d_in[2];
    const float* b1   = (const float*)d_in[3];
    const float* W2   = (const float*)d_in[4];
    const float* b2   = (const float*)d_in[5];
    const float* Wres = (const float*)d_in[6];
    const float* bres = (const float*)d_in[7];
    const float* Wfc1 = (const float*)d_in[8];
    const float* bfc1 = (const float*)d_in[9];
    const float* Wfc2 = (const float*)d_in[10];
    const float* bfc2 = (const float*)d_in[11];

    const int N = in_sizes[0] / 128;
    const int E = in_sizes[1] / 2;
    const int* srcv = eidx;
    const int* dstv = eidx + E;

    float* out  = (float*)d_out;
    float* xout = out;                       // [N,128]
    float* Aout = out + (size_t)N * 128;     // [N]

    // ---- workspace layout ----
    char* p = (char*)d_ws;
    float* dinv  = (float*)p;            p += (size_t)N * 4;
    float* csr_w = (float*)p;            p += (size_t)E * 4;
    u16*  embb   = (u16*)p;              p += (size_t)N * 128 * 2;   // flat [N][128]
    u16*  aggEb  = (u16*)p;              p += (size_t)N * 128 * 2;   // flat [N][128]
    u16*  h2b    = (u16*)p;              p += (size_t)N * 128 * 2;   // flat [N][128]
    u16*  W1t    = (u16*)p;              p += (size_t)512 * 128 * 2;
    u16*  Wct    = (u16*)p;              p += (size_t)256 * 512 * 2;
    u16*  Wfc1t  = (u16*)p;              p += (size_t)256 * 128 * 2;
    int*  cnt     = (int*)p;             p += (size_t)N * 4;
    int*  excl    = (int*)p;             p += (size_t)N * 4;
    int*  rowptr  = (int*)p;             p += (size_t)(N + 1) * 4;
    int*  cursor  = (int*)p;             p += (size_t)N * 4;
    int*  bsum    = (int*)p;             p += 256 * 4;
    int*  csr_src = (int*)p;             p += (size_t)E * 4;

    const int T  = 256;
    const int nb = cdiv_ll(N, 256);      // <= 256 required by scanC2

    // 1) fused setup (also zeroes cnt, inits Aout=bfc2)
    const long long setup_work = (long long)N * 32 + 512 * 128 + 256 * 512
                               + 256 * 128 + (long long)N + (long long)N;
    setup_kernel<<<cdiv_ll(setup_work, T), T, 0, stream>>>(
        emb, W1, W2, Wres, Wfc1, bfc2, embb, W1t, Wct, Wfc1t, cnt, Aout, N);

    // 2) CSR build + dinv
    hist_kernel<<<cdiv_ll(E, T), T, 0, stream>>>(dstv, cnt, E);
    scanA_kernel<<<nb, T, 0, stream>>>(cnt, excl, bsum, N);
    scanC2_kernel<<<nb, T, 0, stream>>>(excl, bsum, cnt, rowptr, cursor, dinv, N, E);
    fill_kernel<<<cdiv_ll(E, T), T, 0, stream>>>(srcv, dstv, dinv, cursor, csr_src, csr_w, E);

    // 3) aggE = S @ emb  (flat bf16)
    aggb_kernel<<<cdiv_ll((long long)N * 64, T), T, 0, stream>>>(
        embb, rowptr, csr_src, csr_w, dinv, aggEb, N);

    // 4) fused GEMM1+GEMM2: h2 = relu(aggE@W1+b1)@W2, hres = relu(...)@Wres
    const size_t lds12 = (size_t)(128 * 136 + 256 * 136 + 128 * 136) * sizeof(u16);
    mgemm12<<<cdiv_ll(N, 128), 512, lds12, stream>>>(
        aggEb, W1t, Wct, b1, N, h2b, xout);

    // 5) fused: x = relu(S@h2 + b2) + hres + bres -> xout (fp32, in-place)
    aggfin_kernel<<<cdiv_ll((long long)N * 64, T), T, 0, stream>>>(
        h2b, rowptr, csr_src, csr_w, dinv, b2, bres, xout, N);

    // 6) head: A += sum relu(x@Wfc1t + bfc1) * Wfc2  (A pre-init to bfc2)
    head_gemm<<<cdiv_ll(N, 128), 512, 0, stream>>>(
        xout, Wfc1t, N, bfc1, Wfc2, Aout);
}